// Round 2
// baseline (916.819 us; speedup 1.0000x reference)
//
#include <hip/hip_runtime.h>
#include <stdint.h>

#define NN 100000
#define EE 1600000
#define NT 98          // ceil(NN/1024)
#define BPH 32         // MHA blocks per head

// fma of scalar xi with float4 vv into acc[base..base+3]
// (param name must NOT be 'x'/'y'/'z'/'w' — member tokens get macro-substituted!)
#define FMA4(xi, vv, a, base)                      \
  a[(base)+0] = fmaf((xi), (vv).x, a[(base)+0]);   \
  a[(base)+1] = fmaf((xi), (vv).y, a[(base)+1]);   \
  a[(base)+2] = fmaf((xi), (vv).z, a[(base)+2]);   \
  a[(base)+3] = fmaf((xi), (vv).w, a[(base)+3]);

// ---------------- degree count ----------------
__global__ void k_deg(const int* __restrict__ ei, int* __restrict__ counts) {
  int e = blockIdx.x * 256 + threadIdx.x;
  if (e < EE) atomicAdd(&counts[ei[EE + e]], 1);
}

// ---------------- block-level scan (Hillis-Steele over 1024) ----------------
__global__ void k_scan_block(const int* __restrict__ counts, int* __restrict__ offsets,
                             int* __restrict__ tile_sums, float* __restrict__ dinv) {
  __shared__ int sm[1024];
  int t = threadIdx.x;
  int i = blockIdx.x * 1024 + t;
  int v = (i < NN) ? counts[i] : 0;
  if (i < NN) dinv[i] = rsqrtf((float)(v + 1));  // deg includes self loop
  sm[t] = v;
  __syncthreads();
  for (int off = 1; off < 1024; off <<= 1) {
    int x = (t >= off) ? sm[t - off] : 0;
    __syncthreads();
    sm[t] += x;
    __syncthreads();
  }
  if (i < NN) offsets[i] = sm[t] - v;  // exclusive within tile
  if (t == 1023) tile_sums[blockIdx.x] = sm[1023];
}

__global__ void k_scan_tiles(int* __restrict__ tile_sums) {
  if (blockIdx.x == 0 && threadIdx.x == 0) {
    int run = 0;
    for (int b = 0; b < NT; b++) { int v = tile_sums[b]; tile_sums[b] = run; run += v; }
  }
}

__global__ void k_scan_add(int* __restrict__ offsets, const int* __restrict__ tile_sums) {
  int i = blockIdx.x * 256 + threadIdx.x;
  if (i < NN) offsets[i] += tile_sums[i >> 10];
  if (i == 0) offsets[NN] = EE;
}

// ---------------- CSR fill (dst-sorted src list) ----------------
__global__ void k_fill(const int* __restrict__ ei, const int* __restrict__ offsets,
                       int* __restrict__ cursor, int* __restrict__ csr_src) {
  int e = blockIdx.x * 256 + threadIdx.x;
  if (e < EE) {
    int s = ei[e], d = ei[EE + e];
    int p = offsets[d] + atomicAdd(&cursor[d], 1);
    csr_src[p] = s;
  }
}

// ---------------- hK = x@WK, hV = x@WV ----------------
__launch_bounds__(256)
__global__ void k_gemm_kv(const float* __restrict__ x, const float* __restrict__ WK,
                          const float* __restrict__ WV, float* __restrict__ hK,
                          float* __restrict__ hV) {
  __shared__ float sK[4096], sV[4096];
  for (int i = threadIdx.x; i < 4096; i += 256) { sK[i] = WK[i]; sV[i] = WV[i]; }
  __syncthreads();
  int row = blockIdx.x * 256 + threadIdx.x;
  if (row >= NN) return;
  const float4* xr = (const float4*)(x + (size_t)row * 64);
  const float4* K4 = (const float4*)sK;
  const float4* V4 = (const float4*)sV;
  float aK[64], aV[64];
#pragma unroll
  for (int j = 0; j < 64; j++) { aK[j] = 0.f; aV[j] = 0.f; }
  for (int i4 = 0; i4 < 16; i4++) {
    float4 xv = xr[i4];
    float xs[4] = {xv.x, xv.y, xv.z, xv.w};
#pragma unroll
    for (int ii = 0; ii < 4; ii++) {
      int i = i4 * 4 + ii;
      float xi = xs[ii];
#pragma unroll
      for (int j4 = 0; j4 < 16; j4++) {
        float4 wk = K4[i * 16 + j4];  // wave-uniform LDS address -> broadcast
        float4 wv = V4[i * 16 + j4];
        FMA4(xi, wk, aK, 4 * j4);
        FMA4(xi, wv, aV, 4 * j4);
      }
    }
  }
  float4* oK = (float4*)(hK + (size_t)row * 64);
  float4* oV = (float4*)(hV + (size_t)row * 64);
#pragma unroll
  for (int j4 = 0; j4 < 16; j4++) {
    oK[j4] = make_float4(aK[4 * j4], aK[4 * j4 + 1], aK[4 * j4 + 2], aK[4 * j4 + 3]);
    oV[j4] = make_float4(aV[4 * j4], aV[4 * j4 + 1], aV[4 * j4 + 2], aV[4 * j4 + 3]);
  }
}

// ---------------- GCN aggregation (wave per node, lane = feature) ----------------
__launch_bounds__(256)
__global__ void k_gcn_agg(const float* __restrict__ hK, const float* __restrict__ hV,
                          const int* __restrict__ offsets, const int* __restrict__ csr_src,
                          const float* __restrict__ dinv, const float* __restrict__ bK,
                          const float* __restrict__ bV, float* __restrict__ xK,
                          float* __restrict__ xV) {
  int gid = blockIdx.x * 256 + threadIdx.x;
  int n = gid >> 6, lane = gid & 63;
  if (n >= NN) return;
  int e0 = offsets[n], e1 = offsets[n + 1];
  float dv = dinv[n];
  float aK = hK[(size_t)n * 64 + lane] * dv * dv;  // self loop
  float aV = hV[(size_t)n * 64 + lane] * dv * dv;
  for (int j = e0; j < e1; j++) {
    int s = csr_src[j];
    float w = dinv[s] * dv;
    aK = fmaf(hK[(size_t)s * 64 + lane], w, aK);
    aV = fmaf(hV[(size_t)s * 64 + lane], w, aV);
  }
  xK[(size_t)n * 64 + lane] = aK + bK[lane];
  xV[(size_t)n * 64 + lane] = aV + bV[lane];
}

// ---------------- qh = (super_Q @ Wq^T + bq) * scale ----------------
__global__ void k_qh(const float* __restrict__ sQ, const float* __restrict__ in_w,
                     const float* __restrict__ in_b, float* __restrict__ qh) {
  int t = blockIdx.x * 256 + threadIdx.x;
  if (t >= 640) return;
  int l = t >> 6, c = t & 63;
  float acc = 0.f;
  for (int i = 0; i < 64; i++) acc = fmaf(sQ[l * 64 + i], in_w[c * 64 + i], acc);
  qh[t] = (acc + in_b[c]) * 0.35355339059327373f;  // 1/sqrt(8)
}

// ---------------- Kh/Vh (head-blocked), hG, s_dst ----------------
// NOTE: hG may alias xK (each thread fully consumes its xK row in phase 1
// before writing its hG row in phase 2; threads touch only their own row).
__launch_bounds__(256)
__global__ void k_gemm2(const float* xK, const float* __restrict__ xV,
                        const float* __restrict__ in_w, const float* __restrict__ in_b,
                        const float* __restrict__ gatW, const float* __restrict__ a_dst,
                        float* __restrict__ Kh, float* __restrict__ Vh, float* hG,
                        float* __restrict__ s_dst) {
  __shared__ float sWk[4096], sWv[4096], sGW[4096];
  __shared__ float sBk[64], sBv[64], sAd[64];
  for (int t = threadIdx.x; t < 4096; t += 256) {
    int c = t & 63, i = t >> 6;
    sWk[i * 64 + c] = in_w[(64 + c) * 64 + i];   // transposed: [i][c]
    sWv[i * 64 + c] = in_w[(128 + c) * 64 + i];
    sGW[t] = gatW[t];                            // natural [i][j]
  }
  for (int t = threadIdx.x; t < 64; t += 256) {
    sBk[t] = in_b[64 + t]; sBv[t] = in_b[128 + t]; sAd[t] = a_dst[t];
  }
  __syncthreads();
  int row = blockIdx.x * 256 + threadIdx.x;
  if (row >= NN) return;
  // phase 1: K row
  {
    const float4* xr = (const float4*)(xK + (size_t)row * 64);
    const float4* W4 = (const float4*)sWk;
    float a[64];
#pragma unroll
    for (int c = 0; c < 64; c++) a[c] = 0.f;
    for (int i4 = 0; i4 < 16; i4++) {
      float4 xv4 = xr[i4];
      float xs[4] = {xv4.x, xv4.y, xv4.z, xv4.w};
#pragma unroll
      for (int ii = 0; ii < 4; ii++) {
        float xi = xs[ii];
        int i = i4 * 4 + ii;
#pragma unroll
        for (int c4 = 0; c4 < 16; c4++) {
          float4 wk = W4[i * 16 + c4];
          FMA4(xi, wk, a, 4 * c4);
        }
      }
    }
#pragma unroll
    for (int h = 0; h < 8; h++) {
      float4* dst = (float4*)(Kh + (size_t)h * NN * 8 + (size_t)row * 8);
      dst[0] = make_float4(a[h * 8 + 0] + sBk[h * 8 + 0], a[h * 8 + 1] + sBk[h * 8 + 1],
                           a[h * 8 + 2] + sBk[h * 8 + 2], a[h * 8 + 3] + sBk[h * 8 + 3]);
      dst[1] = make_float4(a[h * 8 + 4] + sBk[h * 8 + 4], a[h * 8 + 5] + sBk[h * 8 + 5],
                           a[h * 8 + 6] + sBk[h * 8 + 6], a[h * 8 + 7] + sBk[h * 8 + 7]);
    }
  }
  // phase 2: V row + hG row + s_dst
  {
    const float4* xr = (const float4*)(xV + (size_t)row * 64);
    const float4* Wv4 = (const float4*)sWv;
    const float4* G4 = (const float4*)sGW;
    float av[64], ag[64];
#pragma unroll
    for (int c = 0; c < 64; c++) { av[c] = 0.f; ag[c] = 0.f; }
    for (int i4 = 0; i4 < 16; i4++) {
      float4 xv4 = xr[i4];
      float xs[4] = {xv4.x, xv4.y, xv4.z, xv4.w};
#pragma unroll
      for (int ii = 0; ii < 4; ii++) {
        float xi = xs[ii];
        int i = i4 * 4 + ii;
#pragma unroll
        for (int c4 = 0; c4 < 16; c4++) {
          float4 wv = Wv4[i * 16 + c4];
          float4 wg = G4[i * 16 + c4];
          FMA4(xi, wv, av, 4 * c4);
          FMA4(xi, wg, ag, 4 * c4);
        }
      }
    }
#pragma unroll
    for (int h = 0; h < 8; h++) {
      float4* dst = (float4*)(Vh + (size_t)h * NN * 8 + (size_t)row * 8);
      dst[0] = make_float4(av[h * 8 + 0] + sBv[h * 8 + 0], av[h * 8 + 1] + sBv[h * 8 + 1],
                           av[h * 8 + 2] + sBv[h * 8 + 2], av[h * 8 + 3] + sBv[h * 8 + 3]);
      dst[1] = make_float4(av[h * 8 + 4] + sBv[h * 8 + 4], av[h * 8 + 5] + sBv[h * 8 + 5],
                           av[h * 8 + 6] + sBv[h * 8 + 6], av[h * 8 + 7] + sBv[h * 8 + 7]);
    }
    float sd = 0.f;
#pragma unroll
    for (int j = 0; j < 64; j++) sd = fmaf(ag[j], sAd[j], sd);
    s_dst[row] = sd;
    float4* gdst = (float4*)(hG + (size_t)row * 64);
#pragma unroll
    for (int j4 = 0; j4 < 16; j4++)
      gdst[j4] = make_float4(ag[4 * j4], ag[4 * j4 + 1], ag[4 * j4 + 2], ag[4 * j4 + 3]);
  }
}

// ---------------- MHA main: online accumulate exp(logit), exp*v ----------------
__launch_bounds__(256)
__global__ void k_mha(const float* __restrict__ Kh, const float* __restrict__ Vh,
                      const float* __restrict__ qh, float* __restrict__ acc) {
  int h = blockIdx.x / BPH, b = blockIdx.x % BPH;
  __shared__ float sq[80];
  if (threadIdx.x < 80) {
    int l = threadIdx.x >> 3, j = threadIdx.x & 7;
    sq[threadIdx.x] = qh[l * 64 + h * 8 + j];
  }
  __syncthreads();
  const float4* Kp = (const float4*)(Kh + (size_t)h * NN * 8);
  const float4* Vp = (const float4*)(Vh + (size_t)h * NN * 8);
  const float4* sq4 = (const float4*)sq;
  float s[10], o[80];
#pragma unroll
  for (int l = 0; l < 10; l++) s[l] = 0.f;
#pragma unroll
  for (int t = 0; t < 80; t++) o[t] = 0.f;
  for (int n = b * 256 + threadIdx.x; n < NN; n += BPH * 256) {
    float4 k0 = Kp[n * 2], k1 = Kp[n * 2 + 1];
    float4 v0 = Vp[n * 2], v1 = Vp[n * 2 + 1];
#pragma unroll
    for (int l = 0; l < 10; l++) {
      float4 q0 = sq4[l * 2], q1 = sq4[l * 2 + 1];
      float z = q0.x * k0.x + q0.y * k0.y + q0.z * k0.z + q0.w * k0.w +
                q1.x * k1.x + q1.y * k1.y + q1.z * k1.z + q1.w * k1.w;
      float w = __expf(z);  // logits are O(1); no max-subtraction needed
      s[l] += w;
      o[l * 8 + 0] = fmaf(w, v0.x, o[l * 8 + 0]);
      o[l * 8 + 1] = fmaf(w, v0.y, o[l * 8 + 1]);
      o[l * 8 + 2] = fmaf(w, v0.z, o[l * 8 + 2]);
      o[l * 8 + 3] = fmaf(w, v0.w, o[l * 8 + 3]);
      o[l * 8 + 4] = fmaf(w, v1.x, o[l * 8 + 4]);
      o[l * 8 + 5] = fmaf(w, v1.y, o[l * 8 + 5]);
      o[l * 8 + 6] = fmaf(w, v1.z, o[l * 8 + 6]);
      o[l * 8 + 7] = fmaf(w, v1.w, o[l * 8 + 7]);
    }
  }
  int lane = threadIdx.x & 63;
#pragma unroll
  for (int l = 0; l < 10; l++) {
    float v = s[l];
#pragma unroll
    for (int off = 32; off > 0; off >>= 1) v += __shfl_down(v, off);
    if (lane == 0) atomicAdd(&acc[h * 10 + l], v);
  }
#pragma unroll
  for (int t = 0; t < 80; t++) {
    float v = o[t];
#pragma unroll
    for (int off = 32; off > 0; off >>= 1) v += __shfl_down(v, off);
    if (lane == 0) atomicAdd(&acc[80 + h * 80 + t], v);
  }
}

// ---------------- softmax finalize -> cluster -> context -> a_eff ----------------
__global__ void k_context(const float* __restrict__ acc, const float* __restrict__ out_w,
                          const float* __restrict__ out_b, const float* __restrict__ a_src,
                          const float* __restrict__ gat_Wc, float* __restrict__ aeff) {
  __shared__ float po[640], cl[640], ctx[64];
  int t = threadIdx.x;  // blockDim = 640
  {
    int h = t / 80, r = t % 80, l = r >> 3, j = r & 7;
    po[l * 64 + h * 8 + j] = acc[80 + t] / acc[h * 10 + l];
  }
  __syncthreads();
  {
    int l = t >> 6, d = t & 63;
    float v = out_b[d];
    for (int c = 0; c < 64; c++) v = fmaf(po[l * 64 + c], out_w[d * 64 + c], v);
    cl[t] = v;  // cl[l*64+d]
  }
  __syncthreads();
  if (t < 64) {
    float m = 0.f;
#pragma unroll
    for (int l = 0; l < 10; l++) m += cl[l * 64 + t];
    ctx[t] = m * 0.1f;
  }
  __syncthreads();
  if (t < 64) {
    float v = a_src[t];
    for (int i = 0; i < 64; i++) v = fmaf(ctx[i], gat_Wc[i * 64 + t], v);
    aeff[t] = v;
  }
}

// ---------------- s_src[n] = dot(hG[n], a_eff) ----------------
__launch_bounds__(256)
__global__ void k_ssrc(const float* __restrict__ hG, const float* __restrict__ aeff,
                       float* __restrict__ s_src) {
  int gid = blockIdx.x * 256 + threadIdx.x;
  int n = gid >> 6, lane = gid & 63;
  if (n >= NN) return;
  float v = hG[(size_t)n * 64 + lane] * aeff[lane];
#pragma unroll
  for (int off = 32; off > 0; off >>= 1) v += __shfl_xor(v, off);
  if (lane == 0) s_src[n] = v;
}

// ---------------- GAT (wave per node): segment softmax + weighted gather ----------------
__launch_bounds__(256)
__global__ void k_gat(const int* __restrict__ offsets, const int* __restrict__ csr_src,
                      const float* __restrict__ s_src, const float* __restrict__ s_dst,
                      const float* __restrict__ hG, const float* __restrict__ gat_b,
                      float* __restrict__ g) {
  int gid = blockIdx.x * 256 + threadIdx.x;
  int n = gid >> 6, lane = gid & 63;
  if (n >= NN) return;
  int e0 = offsets[n], e1 = offsets[n + 1];
  float sd = s_dst[n];
  float m = -INFINITY;
  for (int base = e0; base < e1; base += 64) {
    int idx = base + lane;
    if (idx < e1) {
      float z = s_src[csr_src[idx]] + sd;
      z = z > 0.f ? z : 0.2f * z;
      m = fmaxf(m, z);
    }
  }
#pragma unroll
  for (int off = 32; off > 0; off >>= 1) m = fmaxf(m, __shfl_xor(m, off));
  float den = 0.f, accO = 0.f;
  for (int base = e0; base < e1; base += 64) {
    int idx = base + lane;
    int cnt = e1 - base; if (cnt > 64) cnt = 64;
    int sidx = 0; float ex = 0.f;
    if (idx < e1) {
      sidx = csr_src[idx];
      float z = s_src[sidx] + sd;
      z = z > 0.f ? z : 0.2f * z;
      ex = __expf(z - m);
      den += ex;
    }
    for (int j = 0; j < cnt; j++) {
      int sj = __shfl(sidx, j);
      float exj = __shfl(ex, j);
      accO = fmaf(exj, hG[(size_t)sj * 64 + lane], accO);
    }
  }
#pragma unroll
  for (int off = 32; off > 0; off >>= 1) den += __shfl_xor(den, off);
  g[(size_t)n * 64 + lane] = accO / (den + 1e-16f) + gat_b[lane];
}

// ---------------- fused MLP: out = relu(relu(g@W1+b1)@W2+b2), in-place on d_out ----------------
__launch_bounds__(256)
__global__ void k_mlp(float* __restrict__ io, const float* __restrict__ W1,
                      const float* __restrict__ b1, const float* __restrict__ W2,
                      const float* __restrict__ b2) {
  __shared__ float sW1[64 * 128];  // transposed: [j][i]
  __shared__ float sW2[128 * 64];  // natural [j][k]
  __shared__ float sb1[128], sb2[64];
  for (int t = threadIdx.x; t < 8192; t += 256) {
    int j = t >> 6, i = t & 63;
    sW1[j * 64 + i] = W1[i * 128 + j];
    sW2[t] = W2[t];
  }
  for (int t = threadIdx.x; t < 128; t += 256) sb1[t] = b1[t];
  for (int t = threadIdx.x; t < 64; t += 256) sb2[t] = b2[t];
  __syncthreads();
  int row = blockIdx.x * 256 + threadIdx.x;
  if (row >= NN) return;
  float4* iop = (float4*)(io + (size_t)row * 64);
  float gr[64];
#pragma unroll
  for (int i4 = 0; i4 < 16; i4++) {
    float4 v = iop[i4];
    gr[4 * i4] = v.x; gr[4 * i4 + 1] = v.y; gr[4 * i4 + 2] = v.z; gr[4 * i4 + 3] = v.w;
  }
  float out[64];
#pragma unroll
  for (int k = 0; k < 64; k++) out[k] = sb2[k];
  const float4* W1t4 = (const float4*)sW1;
  const float4* W24 = (const float4*)sW2;
  for (int j = 0; j < 128; j++) {
    float hv = sb1[j];
#pragma unroll
    for (int i4 = 0; i4 < 16; i4++) {
      float4 wr = W1t4[j * 16 + i4];
      hv = fmaf(gr[4 * i4], wr.x, hv);
      hv = fmaf(gr[4 * i4 + 1], wr.y, hv);
      hv = fmaf(gr[4 * i4 + 2], wr.z, hv);
      hv = fmaf(gr[4 * i4 + 3], wr.w, hv);
    }
    hv = fmaxf(hv, 0.f);
#pragma unroll
    for (int k4 = 0; k4 < 16; k4++) {
      float4 wr = W24[j * 16 + k4];
      FMA4(hv, wr, out, 4 * k4);
    }
  }
#pragma unroll
  for (int k4 = 0; k4 < 16; k4++)
    iop[k4] = make_float4(fmaxf(out[4 * k4], 0.f), fmaxf(out[4 * k4 + 1], 0.f),
                          fmaxf(out[4 * k4 + 2], 0.f), fmaxf(out[4 * k4 + 3], 0.f));
}

// ---------------- host ----------------
extern "C" void kernel_launch(void* const* d_in, const int* in_sizes, int n_in,
                              void* d_out, int out_size, void* d_ws, size_t ws_size,
                              hipStream_t stream) {
  (void)in_sizes; (void)n_in; (void)out_size; (void)ws_size;
  const float* x        = (const float*)d_in[0];
  const int*   ei       = (const int*)d_in[1];
  const float* gcnK_W   = (const float*)d_in[2];
  const float* gcnK_b   = (const float*)d_in[3];
  const float* gcnV_W   = (const float*)d_in[4];
  const float* gcnV_b   = (const float*)d_in[5];
  const float* super_Q  = (const float*)d_in[6];
  const float* mha_in_w = (const float*)d_in[7];
  const float* mha_in_b = (const float*)d_in[8];
  const float* mha_out_w= (const float*)d_in[9];
  const float* mha_out_b= (const float*)d_in[10];
  const float* gat_W    = (const float*)d_in[11];
  const float* gat_Wc   = (const float*)d_in[12];
  const float* gat_a_src= (const float*)d_in[13];
  const float* gat_a_dst= (const float*)d_in[14];
  const float* gat_b    = (const float*)d_in[15];
  const float* t1_W     = (const float*)d_in[16];
  const float* t1_b     = (const float*)d_in[17];
  const float* t2_W     = (const float*)d_in[18];
  const float* t2_b     = (const float*)d_in[19];

  char* ws = (char*)d_ws;
  size_t cur = 0;
  auto alloc = [&](size_t bytes) -> char* {
    char* p = ws + cur;
    cur = (cur + bytes + 255) & ~(size_t)255;
    return p;
  };
  // zero-initialized region (single memset): counts, cursor, mha accumulators
  int*   counts = (int*)alloc((size_t)NN * 4);
  int*   cursor = (int*)alloc((size_t)NN * 4);
  float* macc   = (float*)alloc(720 * 4);
  size_t zero_bytes = cur;
  int*   offsets = (int*)alloc((size_t)(NN + 1) * 4);
  int*   tiles   = (int*)alloc((size_t)NT * 4);
  float* dinv    = (float*)alloc((size_t)NN * 4);
  int*   csr     = (int*)alloc((size_t)EE * 4);
  float* qh      = (float*)alloc(640 * 4);
  float* aeff    = (float*)alloc(64 * 4);
  float* s_src   = (float*)alloc((size_t)NN * 4);
  float* s_dstv  = (float*)alloc((size_t)NN * 4);
  float* hK      = (float*)alloc((size_t)NN * 64 * 4);
  float* hV      = (float*)alloc((size_t)NN * 64 * 4);
  float* xK      = (float*)alloc((size_t)NN * 64 * 4);
  float* xV      = (float*)alloc((size_t)NN * 64 * 4);
  // aliases (lifetimes proven disjoint; see k_gemm2 comment for hG/xK)
  float* Kh = hK;   // hK dead after k_gcn_agg
  float* Vh = hV;   // hV dead after k_gcn_agg
  float* hG = xK;   // per-thread row consume-then-write inside k_gemm2
  float* g  = (float*)d_out;

  (void)hipMemsetAsync(d_ws, 0, zero_bytes, stream);
  k_deg<<<(EE + 255) / 256, 256, 0, stream>>>(ei, counts);
  k_scan_block<<<NT, 1024, 0, stream>>>(counts, offsets, tiles, dinv);
  k_scan_tiles<<<1, 64, 0, stream>>>(tiles);
  k_scan_add<<<(NN + 255) / 256, 256, 0, stream>>>(offsets, tiles);
  k_fill<<<(EE + 255) / 256, 256, 0, stream>>>(ei, offsets, cursor, csr);
  k_gemm_kv<<<(NN + 255) / 256, 256, 0, stream>>>(x, gcnK_W, gcnV_W, hK, hV);
  k_gcn_agg<<<NN / 4, 256, 0, stream>>>(hK, hV, offsets, csr, dinv, gcnK_b, gcnV_b, xK, xV);
  k_qh<<<3, 256, 0, stream>>>(super_Q, mha_in_w, mha_in_b, qh);
  k_gemm2<<<(NN + 255) / 256, 256, 0, stream>>>(xK, xV, mha_in_w, mha_in_b, gat_W, gat_a_dst,
                                                Kh, Vh, hG, s_dstv);
  k_mha<<<8 * BPH, 256, 0, stream>>>(Kh, Vh, qh, macc);
  k_context<<<1, 640, 0, stream>>>(macc, mha_out_w, mha_out_b, gat_a_src, gat_Wc, aeff);
  k_ssrc<<<NN / 4, 256, 0, stream>>>(hG, aeff, s_src);
  k_gat<<<NN / 4, 256, 0, stream>>>(offsets, csr, s_src, s_dstv, hG, gat_b, g);
  k_mlp<<<(NN + 255) / 256, 256, 0, stream>>>(g, t1_W, t1_b, t2_W, t2_b);
}

// Round 3
// 811.050 us; speedup vs baseline: 1.1304x; 1.1304x over previous
//
#include <hip/hip_runtime.h>
#include <hip/hip_bf16.h>
#include <stdint.h>

#define NN 100000
#define EE 1600000
#define NT 98          // ceil(NN/1024)
#define BPH 32         // MHA blocks per head

// fma of scalar xi with float4 vv into acc[base..base+3]
// (param name must NOT be 'x'/'y'/'z'/'w' — member tokens get macro-substituted!)
#define FMA4(xi, vv, a, base)                      \
  a[(base)+0] = fmaf((xi), (vv).x, a[(base)+0]);   \
  a[(base)+1] = fmaf((xi), (vv).y, a[(base)+1]);   \
  a[(base)+2] = fmaf((xi), (vv).z, a[(base)+2]);   \
  a[(base)+3] = fmaf((xi), (vv).w, a[(base)+3]);

__device__ inline unsigned pack_bf2(float a, float b) {
  __hip_bfloat162 t;
  t.x = __float2bfloat16(a);
  t.y = __float2bfloat16(b);
  return *reinterpret_cast<unsigned*>(&t);
}

// ---------------- degree count ----------------
__global__ void k_deg(const int* __restrict__ ei, int* __restrict__ counts) {
  int e = blockIdx.x * 256 + threadIdx.x;
  if (e < EE) atomicAdd(&counts[ei[EE + e]], 1);
}

// ---------------- block-level scan ----------------
__global__ void k_scan_block(const int* __restrict__ counts, int* __restrict__ offsets,
                             int* __restrict__ tile_sums, float* __restrict__ dinv) {
  __shared__ int sm[1024];
  int t = threadIdx.x;
  int i = blockIdx.x * 1024 + t;
  int v = (i < NN) ? counts[i] : 0;
  if (i < NN) dinv[i] = rsqrtf((float)(v + 1));  // deg includes self loop
  sm[t] = v;
  __syncthreads();
  for (int off = 1; off < 1024; off <<= 1) {
    int x = (t >= off) ? sm[t - off] : 0;
    __syncthreads();
    sm[t] += x;
    __syncthreads();
  }
  if (i < NN) offsets[i] = sm[t] - v;
  if (t == 1023) tile_sums[blockIdx.x] = sm[1023];
}

__global__ void k_scan_tiles(int* __restrict__ tile_sums) {
  if (blockIdx.x == 0 && threadIdx.x == 0) {
    int run = 0;
    for (int b = 0; b < NT; b++) { int v = tile_sums[b]; tile_sums[b] = run; run += v; }
  }
}

__global__ void k_scan_add(int* __restrict__ offsets, const int* __restrict__ tile_sums) {
  int i = blockIdx.x * 256 + threadIdx.x;
  if (i < NN) offsets[i] += tile_sums[i >> 10];
  if (i == 0) offsets[NN] = EE;
}

// ---------------- CSR fill (dst-sorted src list) ----------------
__global__ void k_fill(const int* __restrict__ ei, const int* __restrict__ offsets,
                       int* __restrict__ cursor, int* __restrict__ csr_src) {
  int e = blockIdx.x * 256 + threadIdx.x;
  if (e < EE) {
    int s = ei[e], d = ei[EE + e];
    int p = offsets[d] + atomicAdd(&cursor[d], 1);
    csr_src[p] = s;
  }
}

// ---------------- x~ = bf16(x * dinv[row]) ----------------
__global__ void k_prep(const float* __restrict__ x, const float* __restrict__ dinv,
                       unsigned* __restrict__ xbf2) {
  int i = blockIdx.x * 256 + threadIdx.x;  // pair index
  if (i >= NN * 32) return;
  float dv = dinv[i >> 5];
  float2 v = ((const float2*)x)[i];
  xbf2[i] = pack_bf2(v.x * dv, v.y * dv);
}

// ---------------- ax = A_norm @ x (wave per node, half-wave per edge parity) ----------------
__launch_bounds__(256)
__global__ void k_agg_x(const unsigned* __restrict__ xbf2, const int* __restrict__ offsets,
                        const int* __restrict__ csr, const float* __restrict__ dinv,
                        float* __restrict__ ax) {
  int gid = blockIdx.x * 256 + threadIdx.x;
  int n = gid >> 6;
  if (n >= NN) return;
  int lane = gid & 63, l = lane & 31, half = lane >> 5;
  int e0 = offsets[n], e1 = offsets[n + 1];
  float dv = dinv[n];
  float a0 = 0.f, a1 = 0.f;
  {  // self loop (half 0 only): x~[n] already contains x[n]*dv
    unsigned u = xbf2[(size_t)n * 32 + l];
    __hip_bfloat162 v = *reinterpret_cast<__hip_bfloat162*>(&u);
    if (!half) { a0 = __bfloat162float(v.x); a1 = __bfloat162float(v.y); }
  }
  for (int j = e0 + half; j < e1; j += 2) {
    int s = csr[j];
    unsigned u = xbf2[(size_t)s * 32 + l];
    __hip_bfloat162 v = *reinterpret_cast<__hip_bfloat162*>(&u);
    a0 += __bfloat162float(v.x);
    a1 += __bfloat162float(v.y);
  }
  a0 += __shfl_xor(a0, 32);
  a1 += __shfl_xor(a1, 32);
  if (!half) ((float2*)ax)[(size_t)n * 32 + l] = make_float2(a0 * dv, a1 * dv);
}

// ---------------- xK = ax@WK+bK, xV = ax@WV+bV ----------------
__launch_bounds__(256)
__global__ void k_gemm_kv(const float* __restrict__ ax, const float* __restrict__ WK,
                          const float* __restrict__ WV, const float* __restrict__ bK,
                          const float* __restrict__ bV, float* __restrict__ xK,
                          float* __restrict__ xV) {
  __shared__ float sK[4096], sV[4096], sbK[64], sbV[64];
  for (int i = threadIdx.x; i < 4096; i += 256) { sK[i] = WK[i]; sV[i] = WV[i]; }
  for (int i = threadIdx.x; i < 64; i += 256) { sbK[i] = bK[i]; sbV[i] = bV[i]; }
  __syncthreads();
  int row = blockIdx.x * 256 + threadIdx.x;
  if (row >= NN) return;
  const float4* xr = (const float4*)(ax + (size_t)row * 64);
  const float4* K4 = (const float4*)sK;
  const float4* V4 = (const float4*)sV;
  float aK[64], aV[64];
#pragma unroll
  for (int j = 0; j < 64; j++) { aK[j] = 0.f; aV[j] = 0.f; }
  for (int i4 = 0; i4 < 16; i4++) {
    float4 xv = xr[i4];
    float xs[4] = {xv.x, xv.y, xv.z, xv.w};
#pragma unroll
    for (int ii = 0; ii < 4; ii++) {
      int i = i4 * 4 + ii;
      float xi = xs[ii];
#pragma unroll
      for (int j4 = 0; j4 < 16; j4++) {
        float4 wk = K4[i * 16 + j4];
        float4 wv = V4[i * 16 + j4];
        FMA4(xi, wk, aK, 4 * j4);
        FMA4(xi, wv, aV, 4 * j4);
      }
    }
  }
  float4* oK = (float4*)(xK + (size_t)row * 64);
  float4* oV = (float4*)(xV + (size_t)row * 64);
#pragma unroll
  for (int j4 = 0; j4 < 16; j4++) {
    oK[j4] = make_float4(aK[4 * j4] + sbK[4 * j4], aK[4 * j4 + 1] + sbK[4 * j4 + 1],
                         aK[4 * j4 + 2] + sbK[4 * j4 + 2], aK[4 * j4 + 3] + sbK[4 * j4 + 3]);
    oV[j4] = make_float4(aV[4 * j4] + sbV[4 * j4], aV[4 * j4 + 1] + sbV[4 * j4 + 1],
                         aV[4 * j4 + 2] + sbV[4 * j4 + 2], aV[4 * j4 + 3] + sbV[4 * j4 + 3]);
  }
}

// ---------------- qh = (super_Q @ Wq^T + bq) * scale ----------------
__global__ void k_qh(const float* __restrict__ sQ, const float* __restrict__ in_w,
                     const float* __restrict__ in_b, float* __restrict__ qh) {
  int t = blockIdx.x * 256 + threadIdx.x;
  if (t >= 640) return;
  int l = t >> 6, c = t & 63;
  float acc = 0.f;
  for (int i = 0; i < 64; i++) acc = fmaf(sQ[l * 64 + i], in_w[c * 64 + i], acc);
  qh[t] = (acc + in_b[c]) * 0.35355339059327373f;  // 1/sqrt(8)
}

// ---------------- Kh/Vh (head-blocked), hGb (bf16), s_dst ----------------
__launch_bounds__(256)
__global__ void k_gemm2(const float* __restrict__ xK, const float* __restrict__ xV,
                        const float* __restrict__ in_w, const float* __restrict__ in_b,
                        const float* __restrict__ gatW, const float* __restrict__ a_dst,
                        float* __restrict__ Kh, float* __restrict__ Vh,
                        unsigned* __restrict__ hGb, float* __restrict__ s_dst) {
  __shared__ float sWk[4096], sWv[4096], sGW[4096];
  __shared__ float sBk[64], sBv[64], sAd[64];
  for (int t = threadIdx.x; t < 4096; t += 256) {
    int c = t & 63, i = t >> 6;
    sWk[i * 64 + c] = in_w[(64 + c) * 64 + i];   // transposed: [i][c]
    sWv[i * 64 + c] = in_w[(128 + c) * 64 + i];
    sGW[t] = gatW[t];                            // natural [i][j]
  }
  for (int t = threadIdx.x; t < 64; t += 256) {
    sBk[t] = in_b[64 + t]; sBv[t] = in_b[128 + t]; sAd[t] = a_dst[t];
  }
  __syncthreads();
  int row = blockIdx.x * 256 + threadIdx.x;
  if (row >= NN) return;
  // phase 1: K projection
  {
    const float4* xr = (const float4*)(xK + (size_t)row * 64);
    const float4* W4 = (const float4*)sWk;
    float a[64];
#pragma unroll
    for (int c = 0; c < 64; c++) a[c] = 0.f;
    for (int i4 = 0; i4 < 16; i4++) {
      float4 xv4 = xr[i4];
      float xs[4] = {xv4.x, xv4.y, xv4.z, xv4.w};
#pragma unroll
      for (int ii = 0; ii < 4; ii++) {
        float xi = xs[ii];
        int i = i4 * 4 + ii;
#pragma unroll
        for (int c4 = 0; c4 < 16; c4++) {
          float4 wk = W4[i * 16 + c4];
          FMA4(xi, wk, a, 4 * c4);
        }
      }
    }
#pragma unroll
    for (int h = 0; h < 8; h++) {
      float4* dst = (float4*)(Kh + (size_t)h * NN * 8 + (size_t)row * 8);
      dst[0] = make_float4(a[h * 8 + 0] + sBk[h * 8 + 0], a[h * 8 + 1] + sBk[h * 8 + 1],
                           a[h * 8 + 2] + sBk[h * 8 + 2], a[h * 8 + 3] + sBk[h * 8 + 3]);
      dst[1] = make_float4(a[h * 8 + 4] + sBk[h * 8 + 4], a[h * 8 + 5] + sBk[h * 8 + 5],
                           a[h * 8 + 6] + sBk[h * 8 + 6], a[h * 8 + 7] + sBk[h * 8 + 7]);
    }
  }
  // phase 2: V projection + GAT features + s_dst
  {
    const float4* xr = (const float4*)(xV + (size_t)row * 64);
    const float4* Wv4 = (const float4*)sWv;
    const float4* G4 = (const float4*)sGW;
    float av[64], ag[64];
#pragma unroll
    for (int c = 0; c < 64; c++) { av[c] = 0.f; ag[c] = 0.f; }
    for (int i4 = 0; i4 < 16; i4++) {
      float4 xv4 = xr[i4];
      float xs[4] = {xv4.x, xv4.y, xv4.z, xv4.w};
#pragma unroll
      for (int ii = 0; ii < 4; ii++) {
        float xi = xs[ii];
        int i = i4 * 4 + ii;
#pragma unroll
        for (int c4 = 0; c4 < 16; c4++) {
          float4 wv = Wv4[i * 16 + c4];
          float4 wg = G4[i * 16 + c4];
          FMA4(xi, wv, av, 4 * c4);
          FMA4(xi, wg, ag, 4 * c4);
        }
      }
    }
#pragma unroll
    for (int h = 0; h < 8; h++) {
      float4* dst = (float4*)(Vh + (size_t)h * NN * 8 + (size_t)row * 8);
      dst[0] = make_float4(av[h * 8 + 0] + sBv[h * 8 + 0], av[h * 8 + 1] + sBv[h * 8 + 1],
                           av[h * 8 + 2] + sBv[h * 8 + 2], av[h * 8 + 3] + sBv[h * 8 + 3]);
      dst[1] = make_float4(av[h * 8 + 4] + sBv[h * 8 + 4], av[h * 8 + 5] + sBv[h * 8 + 5],
                           av[h * 8 + 6] + sBv[h * 8 + 6], av[h * 8 + 7] + sBv[h * 8 + 7]);
    }
    float sd = 0.f;
#pragma unroll
    for (int j = 0; j < 64; j++) sd = fmaf(ag[j], sAd[j], sd);
    s_dst[row] = sd;
    uint4* gb4 = (uint4*)(hGb + (size_t)row * 32);
#pragma unroll
    for (int q = 0; q < 8; q++) {
      uint4 u;
      u.x = pack_bf2(ag[8 * q + 0], ag[8 * q + 1]);
      u.y = pack_bf2(ag[8 * q + 2], ag[8 * q + 3]);
      u.z = pack_bf2(ag[8 * q + 4], ag[8 * q + 5]);
      u.w = pack_bf2(ag[8 * q + 6], ag[8 * q + 7]);
      gb4[q] = u;
    }
  }
}

// ---------------- MHA main ----------------
__launch_bounds__(256)
__global__ void k_mha(const float* __restrict__ Kh, const float* __restrict__ Vh,
                      const float* __restrict__ qh, float* __restrict__ acc) {
  int h = blockIdx.x / BPH, b = blockIdx.x % BPH;
  __shared__ float sq[80];
  if (threadIdx.x < 80) {
    int l = threadIdx.x >> 3, j = threadIdx.x & 7;
    sq[threadIdx.x] = qh[l * 64 + h * 8 + j];
  }
  __syncthreads();
  const float4* Kp = (const float4*)(Kh + (size_t)h * NN * 8);
  const float4* Vp = (const float4*)(Vh + (size_t)h * NN * 8);
  const float4* sq4 = (const float4*)sq;
  float s[10], o[80];
#pragma unroll
  for (int l = 0; l < 10; l++) s[l] = 0.f;
#pragma unroll
  for (int t = 0; t < 80; t++) o[t] = 0.f;
  for (int n = b * 256 + threadIdx.x; n < NN; n += BPH * 256) {
    float4 k0 = Kp[n * 2], k1 = Kp[n * 2 + 1];
    float4 v0 = Vp[n * 2], v1 = Vp[n * 2 + 1];
#pragma unroll
    for (int l = 0; l < 10; l++) {
      float4 q0 = sq4[l * 2], q1 = sq4[l * 2 + 1];
      float z = q0.x * k0.x + q0.y * k0.y + q0.z * k0.z + q0.w * k0.w +
                q1.x * k1.x + q1.y * k1.y + q1.z * k1.z + q1.w * k1.w;
      float w = __expf(z);
      s[l] += w;
      o[l * 8 + 0] = fmaf(w, v0.x, o[l * 8 + 0]);
      o[l * 8 + 1] = fmaf(w, v0.y, o[l * 8 + 1]);
      o[l * 8 + 2] = fmaf(w, v0.z, o[l * 8 + 2]);
      o[l * 8 + 3] = fmaf(w, v0.w, o[l * 8 + 3]);
      o[l * 8 + 4] = fmaf(w, v1.x, o[l * 8 + 4]);
      o[l * 8 + 5] = fmaf(w, v1.y, o[l * 8 + 5]);
      o[l * 8 + 6] = fmaf(w, v1.z, o[l * 8 + 6]);
      o[l * 8 + 7] = fmaf(w, v1.w, o[l * 8 + 7]);
    }
  }
  int lane = threadIdx.x & 63;
#pragma unroll
  for (int l = 0; l < 10; l++) {
    float v = s[l];
#pragma unroll
    for (int off = 32; off > 0; off >>= 1) v += __shfl_down(v, off);
    if (lane == 0) atomicAdd(&acc[h * 10 + l], v);
  }
#pragma unroll
  for (int t = 0; t < 80; t++) {
    float v = o[t];
#pragma unroll
    for (int off = 32; off > 0; off >>= 1) v += __shfl_down(v, off);
    if (lane == 0) atomicAdd(&acc[80 + h * 80 + t], v);
  }
}

// ---------------- softmax finalize -> cluster -> context -> a_eff ----------------
__global__ void k_context(const float* __restrict__ acc, const float* __restrict__ out_w,
                          const float* __restrict__ out_b, const float* __restrict__ a_src,
                          const float* __restrict__ gat_Wc, float* __restrict__ aeff) {
  __shared__ float po[640], cl[640], ctx[64];
  int t = threadIdx.x;  // blockDim = 640
  {
    int h = t / 80, r = t % 80, l = r >> 3, j = r & 7;
    po[l * 64 + h * 8 + j] = acc[80 + t] / acc[h * 10 + l];
  }
  __syncthreads();
  {
    int l = t >> 6, d = t & 63;
    float v = out_b[d];
    for (int c = 0; c < 64; c++) v = fmaf(po[l * 64 + c], out_w[d * 64 + c], v);
    cl[t] = v;
  }
  __syncthreads();
  if (t < 64) {
    float m = 0.f;
#pragma unroll
    for (int l = 0; l < 10; l++) m += cl[l * 64 + t];
    ctx[t] = m * 0.1f;
  }
  __syncthreads();
  if (t < 64) {
    float v = a_src[t];
    for (int i = 0; i < 64; i++) v = fmaf(ctx[i], gat_Wc[i * 64 + t], v);
    aeff[t] = v;
  }
}

// ---------------- s_src[n] = dot(hG[n], a_eff) ----------------
__launch_bounds__(256)
__global__ void k_ssrc(const unsigned* __restrict__ hGb, const float* __restrict__ aeff,
                       float* __restrict__ s_src) {
  int gid = blockIdx.x * 256 + threadIdx.x;
  int n = gid >> 6, lane = gid & 63;
  if (n >= NN) return;
  const __hip_bfloat16* hp = (const __hip_bfloat16*)hGb;
  float v = __bfloat162float(hp[(size_t)n * 64 + lane]) * aeff[lane];
#pragma unroll
  for (int off = 32; off > 0; off >>= 1) v += __shfl_xor(v, off);
  if (lane == 0) s_src[n] = v;
}

// ---------------- GAT: single-sweep segment softmax + bf16 weighted gather ----------------
__launch_bounds__(256)
__global__ void k_gat(const int* __restrict__ offsets, const int* __restrict__ csr,
                      const float* __restrict__ s_src, const float* __restrict__ s_dstv,
                      const unsigned* __restrict__ hGb, const float* __restrict__ gat_b,
                      float* __restrict__ g) {
  int gid = blockIdx.x * 256 + threadIdx.x;
  int n = gid >> 6;
  if (n >= NN) return;
  int lane = gid & 63, l = lane & 31, half = lane >> 5;
  int e0 = offsets[n], e1 = offsets[n + 1];
  float sd = s_dstv[n];
  float den = 0.f, a0 = 0.f, a1 = 0.f;
  for (int j = e0 + half; j < e1; j += 2) {
    int s = csr[j];
    float z = s_src[s] + sd;
    z = z > 0.f ? z : 0.2f * z;
    float ex = __expf(z);   // logits O(1): softmax is shift-invariant, skip segment-max
    den += ex;
    unsigned u = hGb[(size_t)s * 32 + l];
    __hip_bfloat162 v = *reinterpret_cast<__hip_bfloat162*>(&u);
    a0 = fmaf(ex, __bfloat162float(v.x), a0);
    a1 = fmaf(ex, __bfloat162float(v.y), a1);
  }
  den += __shfl_xor(den, 32);
  a0 += __shfl_xor(a0, 32);
  a1 += __shfl_xor(a1, 32);
  float inv = 1.f / (den + 1e-16f);
  if (!half)
    ((float2*)g)[(size_t)n * 32 + l] =
        make_float2(a0 * inv + gat_b[2 * l], a1 * inv + gat_b[2 * l + 1]);
}

// ---------------- fused MLP (in-place on d_out) ----------------
__launch_bounds__(256)
__global__ void k_mlp(float* __restrict__ io, const float* __restrict__ W1,
                      const float* __restrict__ b1, const float* __restrict__ W2,
                      const float* __restrict__ b2) {
  __shared__ float sW1[64 * 128];  // transposed: [j][i]
  __shared__ float sW2[128 * 64];  // natural [j][k]
  __shared__ float sb1[128], sb2[64];
  for (int t = threadIdx.x; t < 8192; t += 256) {
    int j = t >> 6, i = t & 63;
    sW1[j * 64 + i] = W1[i * 128 + j];
    sW2[t] = W2[t];
  }
  for (int t = threadIdx.x; t < 128; t += 256) sb1[t] = b1[t];
  for (int t = threadIdx.x; t < 64; t += 256) sb2[t] = b2[t];
  __syncthreads();
  int row = blockIdx.x * 256 + threadIdx.x;
  if (row >= NN) return;
  float4* iop = (float4*)(io + (size_t)row * 64);
  float gr[64];
#pragma unroll
  for (int i4 = 0; i4 < 16; i4++) {
    float4 v = iop[i4];
    gr[4 * i4] = v.x; gr[4 * i4 + 1] = v.y; gr[4 * i4 + 2] = v.z; gr[4 * i4 + 3] = v.w;
  }
  float out[64];
#pragma unroll
  for (int k = 0; k < 64; k++) out[k] = sb2[k];
  const float4* W1t4 = (const float4*)sW1;
  const float4* W24 = (const float4*)sW2;
  for (int j = 0; j < 128; j++) {
    float hv = sb1[j];
#pragma unroll
    for (int i4 = 0; i4 < 16; i4++) {
      float4 wr = W1t4[j * 16 + i4];
      hv = fmaf(gr[4 * i4], wr.x, hv);
      hv = fmaf(gr[4 * i4 + 1], wr.y, hv);
      hv = fmaf(gr[4 * i4 + 2], wr.z, hv);
      hv = fmaf(gr[4 * i4 + 3], wr.w, hv);
    }
    hv = fmaxf(hv, 0.f);
#pragma unroll
    for (int k4 = 0; k4 < 16; k4++) {
      float4 wr = W24[j * 16 + k4];
      FMA4(hv, wr, out, 4 * k4);
    }
  }
#pragma unroll
  for (int k4 = 0; k4 < 16; k4++)
    iop[k4] = make_float4(fmaxf(out[4 * k4], 0.f), fmaxf(out[4 * k4 + 1], 0.f),
                          fmaxf(out[4 * k4 + 2], 0.f), fmaxf(out[4 * k4 + 3], 0.f));
}

// ---------------- host ----------------
extern "C" void kernel_launch(void* const* d_in, const int* in_sizes, int n_in,
                              void* d_out, int out_size, void* d_ws, size_t ws_size,
                              hipStream_t stream) {
  (void)in_sizes; (void)n_in; (void)out_size; (void)ws_size;
  const float* x        = (const float*)d_in[0];
  const int*   ei       = (const int*)d_in[1];
  const float* gcnK_W   = (const float*)d_in[2];
  const float* gcnK_b   = (const float*)d_in[3];
  const float* gcnV_W   = (const float*)d_in[4];
  const float* gcnV_b   = (const float*)d_in[5];
  const float* super_Q  = (const float*)d_in[6];
  const float* mha_in_w = (const float*)d_in[7];
  const float* mha_in_b = (const float*)d_in[8];
  const float* mha_out_w= (const float*)d_in[9];
  const float* mha_out_b= (const float*)d_in[10];
  const float* gat_W    = (const float*)d_in[11];
  const float* gat_Wc   = (const float*)d_in[12];
  const float* gat_a_src= (const float*)d_in[13];
  const float* gat_a_dst= (const float*)d_in[14];
  const float* gat_b    = (const float*)d_in[15];
  const float* t1_W     = (const float*)d_in[16];
  const float* t1_b     = (const float*)d_in[17];
  const float* t2_W     = (const float*)d_in[18];
  const float* t2_b     = (const float*)d_in[19];

  char* ws = (char*)d_ws;
  size_t cur = 0;
  auto alloc = [&](size_t bytes) -> char* {
    char* p = ws + cur;
    cur = (cur + bytes + 255) & ~(size_t)255;
    return p;
  };
  // zero-initialized region (single memset): counts, cursor, mha accumulators
  int*      counts = (int*)alloc((size_t)NN * 4);
  int*      cursor = (int*)alloc((size_t)NN * 4);
  float*    macc   = (float*)alloc(720 * 4);
  size_t zero_bytes = cur;
  int*      offsets = (int*)alloc((size_t)(NN + 1) * 4);
  int*      tiles   = (int*)alloc((size_t)NT * 4);
  float*    dinv    = (float*)alloc((size_t)NN * 4);
  int*      csr     = (int*)alloc((size_t)EE * 4);
  float*    qh      = (float*)alloc(640 * 4);
  float*    aeff    = (float*)alloc(64 * 4);
  float*    s_src   = (float*)alloc((size_t)NN * 4);
  float*    s_dstv  = (float*)alloc((size_t)NN * 4);
  unsigned* xbf     = (unsigned*)alloc((size_t)NN * 128);   // bf16 x*dinv, 32 pairs/row
  float*    ax      = (float*)alloc((size_t)NN * 64 * 4);
  float*    xK      = (float*)alloc((size_t)NN * 64 * 4);
  float*    xV      = (float*)alloc((size_t)NN * 64 * 4);
  float*    Vh      = (float*)alloc((size_t)NN * 64 * 4);
  unsigned* hGb     = (unsigned*)alloc((size_t)NN * 128);   // bf16 GAT features
  float*    Kh      = ax;   // ax dead after k_gemm_kv; k_gemm2 writes Kh there
  float*    g       = (float*)d_out;

  (void)hipMemsetAsync(d_ws, 0, zero_bytes, stream);
  k_deg<<<(EE + 255) / 256, 256, 0, stream>>>(ei, counts);
  k_scan_block<<<NT, 1024, 0, stream>>>(counts, offsets, tiles, dinv);
  k_scan_tiles<<<1, 64, 0, stream>>>(tiles);
  k_scan_add<<<(NN + 255) / 256, 256, 0, stream>>>(offsets, tiles);
  k_fill<<<(EE + 255) / 256, 256, 0, stream>>>(ei, offsets, cursor, csr);
  k_prep<<<(NN * 32 + 255) / 256, 256, 0, stream>>>(x, dinv, xbf);
  k_agg_x<<<NN / 4, 256, 0, stream>>>(xbf, offsets, csr, dinv, ax);
  k_gemm_kv<<<(NN + 255) / 256, 256, 0, stream>>>(ax, gcnK_W, gcnV_W, gcnK_b, gcnV_b, xK, xV);
  k_qh<<<3, 256, 0, stream>>>(super_Q, mha_in_w, mha_in_b, qh);
  k_gemm2<<<(NN + 255) / 256, 256, 0, stream>>>(xK, xV, mha_in_w, mha_in_b, gat_W, gat_a_dst,
                                                Kh, Vh, hGb, s_dstv);
  k_mha<<<8 * BPH, 256, 0, stream>>>(Kh, Vh, qh, macc);
  k_context<<<1, 640, 0, stream>>>(macc, mha_out_w, mha_out_b, gat_a_src, gat_Wc, aeff);
  k_ssrc<<<NN / 4, 256, 0, stream>>>(hGb, aeff, s_src);
  k_gat<<<NN / 4, 256, 0, stream>>>(offsets, csr, s_src, s_dstv, hGb, gat_b, g);
  k_mlp<<<(NN + 255) / 256, 256, 0, stream>>>(g, t1_W, t1_b, t2_W, t2_b);
}